// Round 1
// baseline (609.603 us; speedup 1.0000x reference)
//
#include <hip/hip_runtime.h>

// Problem constants (fixed by setup_inputs): E=800000, N=50000, G=16, EMB=64.
#define EMB 64

// ---------------------------------------------------------------------------
// Kernel 0: transpose W1 [in=64, out=64] -> W1T[o*64+i] so the per-output
// column becomes a contiguous row (wave-uniform scalar loads in edge kernel).
// ---------------------------------------------------------------------------
__global__ void transpose_w1(const float* __restrict__ W1, float* __restrict__ W1T) {
    int t = blockIdx.x * blockDim.x + threadIdx.x;   // 4096 threads
    int o = t >> 6, i = t & 63;
    W1T[t] = W1[i * 64 + o];                          // t = o*64 + i
}

// ---------------------------------------------------------------------------
// Kernel 1: per-edge fused  y = x@W1 ; edge_out_c = sum_o W2[o]*silu(a_c*y_o+b_o) + b2
// using only the 6 unique symmetric components a_c of d (x) d.
// Atomically accumulates per-node sums (6 floats) + per-node edge count.
// ---------------------------------------------------------------------------
__global__ __launch_bounds__(256) void edge_kernel(
    const float* __restrict__ dvec, const float* __restrict__ x_edge,
    const int*   __restrict__ eidx,
    const float* __restrict__ W1T, const float* __restrict__ b1,
    const float* __restrict__ W2,  const float* __restrict__ b2,
    float* __restrict__ node_sum, float* __restrict__ node_cnt, int E)
{
    int e = blockIdx.x * blockDim.x + threadIdx.x;
    if (e >= E) return;

    float d0 = dvec[3 * e + 0];
    float d1 = dvec[3 * e + 1];
    float d2 = dvec[3 * e + 2];
    // 6 unique components of the symmetric outer product d (x) d
    float a[6] = { d0 * d0, d1 * d1, d2 * d2, d0 * d1, d0 * d2, d1 * d2 };

    // Load this edge's x row (64 floats) into registers via float4.
    float x[EMB];
    const float4* xr = (const float4*)(x_edge + (size_t)e * EMB);
    #pragma unroll
    for (int k = 0; k < EMB / 4; ++k) {
        float4 v = xr[k];
        x[4 * k + 0] = v.x; x[4 * k + 1] = v.y;
        x[4 * k + 2] = v.z; x[4 * k + 3] = v.w;
    }

    float bb2 = b2[0];
    float acc[6] = { bb2, bb2, bb2, bb2, bb2, bb2 };

    const float NL2E = -1.442695040888963f;  // -log2(e)

    for (int o = 0; o < EMB; ++o) {
        // y_o = x . W1[:,o]  — W1T row o is wave-uniform -> scalar loads.
        const float* w = W1T + o * EMB;
        float y0 = 0.f, y1 = 0.f, y2 = 0.f, y3 = 0.f;
        #pragma unroll
        for (int i = 0; i < EMB; i += 4) {
            y0 = fmaf(x[i + 0], w[i + 0], y0);
            y1 = fmaf(x[i + 1], w[i + 1], y1);
            y2 = fmaf(x[i + 2], w[i + 2], y2);
            y3 = fmaf(x[i + 3], w[i + 3], y3);
        }
        float y  = (y0 + y1) + (y2 + y3);
        float b  = b1[o];
        float w2 = W2[o];
        float yl = y * NL2E;
        float bl = b * NL2E;
        #pragma unroll
        for (int c = 0; c < 6; ++c) {
            float t  = fmaf(a[c], yl, bl);                  // -z*log2(e)
            float ex = __builtin_amdgcn_exp2f(t);           // e^{-z}
            float r  = __builtin_amdgcn_rcpf(1.0f + ex);    // sigmoid(z)
            float z  = fmaf(a[c], y, b);
            acc[c]   = fmaf(w2, z * r, acc[c]);             // += W2[o]*silu(z)
        }
    }

    int n = eidx[e];
    float* p = node_sum + (size_t)n * 6;
    #pragma unroll
    for (int c = 0; c < 6; ++c) atomicAdd(p + c, acc[c]);
    atomicAdd(node_cnt + n, 1.0f);
}

// ---------------------------------------------------------------------------
// Kernel 2: node means -> per-graph sums via LDS bins (batch sorted, G=16).
// Counts ALL nodes per graph (matches ref: ones summed over every node).
// ---------------------------------------------------------------------------
__global__ __launch_bounds__(256) void node_kernel(
    const float* __restrict__ node_sum, const float* __restrict__ node_cnt,
    const int* __restrict__ batch,
    float* __restrict__ gsum, float* __restrict__ gcnt, int N)
{
    __shared__ float ls[16 * 6];
    __shared__ float lc[16];
    int t = threadIdx.x;
    if (t < 96) ls[t] = 0.f;
    if (t < 16) lc[t] = 0.f;
    __syncthreads();

    int n = blockIdx.x * blockDim.x + t;
    if (n < N) {
        float cnt = node_cnt[n];
        float inv = 1.0f / fmaxf(cnt, 1.0f);   // s / max(c,1); zero-edge node sums are 0
        int g = batch[n];
        #pragma unroll
        for (int c = 0; c < 6; ++c)
            atomicAdd(&ls[g * 6 + c], node_sum[(size_t)n * 6 + c] * inv);
        atomicAdd(&lc[g], 1.0f);
    }
    __syncthreads();
    if (t < 96) atomicAdd(gsum + t, ls[t]);
    if (t < 16) atomicAdd(gcnt + t, lc[t]);
}

// ---------------------------------------------------------------------------
// Kernel 3: finalize — graph means, expand 6 symmetric comps -> 9, write [16,9].
// ---------------------------------------------------------------------------
__global__ void final_kernel(const float* __restrict__ gsum,
                             const float* __restrict__ gcnt,
                             float* __restrict__ out)
{
    int g = threadIdx.x;
    if (g >= 16) return;
    float inv = 1.0f / fmaxf(gcnt[g], 1.0f);
    float m0 = gsum[g * 6 + 0] * inv;  // d0d0
    float m1 = gsum[g * 6 + 1] * inv;  // d1d1
    float m2 = gsum[g * 6 + 2] * inv;  // d2d2
    float m3 = gsum[g * 6 + 3] * inv;  // d0d1
    float m4 = gsum[g * 6 + 4] * inv;  // d0d2
    float m5 = gsum[g * 6 + 5] * inv;  // d1d2
    float* p = out + g * 9;
    p[0] = m0; p[1] = m3; p[2] = m4;
    p[3] = m3; p[4] = m1; p[5] = m5;
    p[6] = m4; p[7] = m5; p[8] = m2;
}

// ---------------------------------------------------------------------------
extern "C" void kernel_launch(void* const* d_in, const int* in_sizes, int n_in,
                              void* d_out, int out_size, void* d_ws, size_t ws_size,
                              hipStream_t stream) {
    const float* dvec   = (const float*)d_in[0];   // [E,3]
    const float* x_edge = (const float*)d_in[1];   // [E,64]
    const int*   eidx   = (const int*)d_in[2];     // [E]
    const int*   batch  = (const int*)d_in[3];     // [N] sorted
    // d_in[4]=n_nodes, d_in[5]=n_graphs (device scalars; sizes known from in_sizes / problem)
    const float* W1     = (const float*)d_in[6];   // [64,64] (in,out)
    const float* b1     = (const float*)d_in[7];   // [64]
    const float* W2     = (const float*)d_in[8];   // [64,1]
    const float* b2     = (const float*)d_in[9];   // [1]

    int E = in_sizes[0] / 3;
    int N = in_sizes[3];

    float* ws       = (float*)d_ws;
    float* node_sum = ws;                         // N*6
    float* node_cnt = ws + (size_t)N * 6;         // N
    float* gsum     = node_cnt + N;               // 16*6 = 96
    float* gcnt     = gsum + 96;                  // 16
    float* W1T      = gcnt + 16;                  // 4096 (no zero-init needed)

    size_t zero_bytes = ((size_t)N * 7 + 112) * sizeof(float);
    hipMemsetAsync(d_ws, 0, zero_bytes, stream);

    transpose_w1<<<16, 256, 0, stream>>>(W1, W1T);
    edge_kernel<<<(E + 255) / 256, 256, 0, stream>>>(dvec, x_edge, eidx, W1T, b1, W2, b2,
                                                     node_sum, node_cnt, E);
    node_kernel<<<(N + 255) / 256, 256, 0, stream>>>(node_sum, node_cnt, batch, gsum, gcnt, N);
    final_kernel<<<1, 64, 0, stream>>>(gsum, gcnt, (float*)d_out);
}